// Round 2
// baseline (132.342 us; speedup 1.0000x reference)
//
#include <hip/hip_runtime.h>

#define B_TOTAL  1024
#define NGRID    294912
#define BTILE    32
#define NB_B     (B_TOTAL / BTILE)        // 32 b-tiles
#define NB_N     36                       // n-chunks
#define NCHUNK   (NGRID / NB_N)           // 8192 n per chunk
#define NPERITER 1024                     // n staged per block iteration
#define NITERS   (NCHUNK / NPERITER)      // 8
#define NUNROLL  4                        // n per thread per iteration

// Phase 1: partial argmax over each (b-tile, n-chunk).
__global__ __launch_bounds__(256, 2)
void so3_partial_kernel(const float* __restrict__ A,   // [1024][9]
                        const float* __restrict__ G,   // [NGRID][9]
                        float* __restrict__ pval,      // [NB_N][B_TOTAL]
                        int*   __restrict__ pidx)      // [NB_N][B_TOTAL]
{
    __shared__ __align__(16) float sA[BTILE * 12];       // stride 12: 16B-aligned rows
    __shared__ __align__(16) float sG[NPERITER * 9];     // 36 KB staging
    __shared__ float sRv[4][BTILE];
    __shared__ int   sRi[4][BTILE];

    const int t     = threadIdx.x;
    const int chunk = blockIdx.x;
    const int btile = blockIdx.y;

    // BTILE*9 = 288 > blockDim (256): must stride. (Round-1 bug: tail rows
    // 28..31 were never staged.)
    for (int idx = t; idx < BTILE * 9; idx += 256) {
        int b = idx / 9, k = idx - b * 9;
        sA[b * 12 + k] = A[(btile * BTILE + b) * 9 + k];
    }

    float best[BTILE];
    int   bidx[BTILE];
    #pragma unroll
    for (int b = 0; b < BTILE; ++b) { best[b] = -1e30f; bidx[b] = 0; }

    const int chunk_n0 = chunk * NCHUNK;

    for (int it = 0; it < NITERS; ++it) {
        const int nbase = chunk_n0 + it * NPERITER;
        __syncthreads();   // protect previous iteration's sG reads (and sA writes, it==0)
        {
            // 1024 mats * 9 floats = 2304 float4; 9 coalesced float4 per thread.
            const float4* gsrc = (const float4*)(G + (size_t)nbase * 9);
            float4*       gdst = (float4*)sG;
            #pragma unroll
            for (int j = 0; j < 9; ++j)
                gdst[j * 256 + t] = gsrc[j * 256 + t];
        }
        __syncthreads();

        // this thread's 4 grid mats -> 36 registers (t*36 floats = t*144 B, aligned)
        float gr[NUNROLL * 9];
        {
            const float4* gv = (const float4*)(sG + t * (NUNROLL * 9));
            #pragma unroll
            for (int j = 0; j < 9; ++j)
                *(float4*)&gr[j * 4] = gv[j];
        }
        const int n0 = nbase + t * NUNROLL;

        #pragma unroll
        for (int b = 0; b < BTILE; ++b) {
            const float4* av = (const float4*)(sA + b * 12);
            float4 a0 = av[0], a1 = av[1], a2 = av[2];   // 3x ds_read_b128, broadcast
            #pragma unroll
            for (int u = 0; u < NUNROLL; ++u) {
                const float* g = &gr[u * 9];
                float d;
                d = a0.x * g[0];
                d = fmaf(a0.y, g[1], d);
                d = fmaf(a0.z, g[2], d);
                d = fmaf(a0.w, g[3], d);
                d = fmaf(a1.x, g[4], d);
                d = fmaf(a1.y, g[5], d);
                d = fmaf(a1.z, g[6], d);
                d = fmaf(a1.w, g[7], d);
                d = fmaf(a2.x, g[8], d);
                if (d > best[b]) { best[b] = d; bidx[b] = n0 + u; }
            }
        }
    }

    // per-wave butterfly reduce (keep lowest index on ties, matching np.argmax)
    #pragma unroll
    for (int b = 0; b < BTILE; ++b) {
        float v = best[b]; int i = bidx[b];
        #pragma unroll
        for (int s = 32; s > 0; s >>= 1) {
            float v2 = __shfl_xor(v, s);
            int   i2 = __shfl_xor(i, s);
            if (v2 > v || (v2 == v && i2 < i)) { v = v2; i = i2; }
        }
        best[b] = v; bidx[b] = i;
    }
    const int wave = t >> 6;
    if ((t & 63) == 0) {
        #pragma unroll
        for (int b = 0; b < BTILE; ++b) { sRv[wave][b] = best[b]; sRi[wave][b] = bidx[b]; }
    }
    __syncthreads();
    if (t < BTILE) {
        float v = sRv[0][t]; int i = sRi[0][t];
        #pragma unroll
        for (int w = 1; w < 4; ++w) {
            float v2 = sRv[w][t]; int i2 = sRi[w][t];
            if (v2 > v || (v2 == v && i2 < i)) { v = v2; i = i2; }
        }
        pval[chunk * B_TOTAL + btile * BTILE + t] = v;
        pidx[chunk * B_TOTAL + btile * BTILE + t] = i;
    }
}

// Phase 2: reduce the NB_N partials per b, write dot_trace and gather nearest.
__global__ __launch_bounds__(64)
void so3_final_kernel(const float* __restrict__ G,
                      const float* __restrict__ pval,
                      const int*   __restrict__ pidx,
                      float* __restrict__ out)   // [1024] trace, then [1024*9] nearest
{
    const int b = blockIdx.x;
    const int t = threadIdx.x;
    float v = -1e30f; int i = 0;
    if (t < NB_N) { v = pval[t * B_TOTAL + b]; i = pidx[t * B_TOTAL + b]; }
    #pragma unroll
    for (int s = 32; s > 0; s >>= 1) {
        float v2 = __shfl_xor(v, s);
        int   i2 = __shfl_xor(i, s);
        if (v2 > v || (v2 == v && i2 < i)) { v = v2; i = i2; }
    }
    if (t == 0) out[b] = v;
    if (t < 9) out[B_TOTAL + b * 9 + t] = G[(size_t)i * 9 + t];
}

extern "C" void kernel_launch(void* const* d_in, const int* in_sizes, int n_in,
                              void* d_out, int out_size, void* d_ws, size_t ws_size,
                              hipStream_t stream) {
    const float* A = (const float*)d_in[0];   // rotMat [1024,3,3] fp32
    const float* G = (const float*)d_in[1];   // output_rotmats [294912,3,3] fp32
    float* out  = (float*)d_out;
    float* pval = (float*)d_ws;                               // 36*1024 floats
    int*   pidx = (int*)((float*)d_ws + NB_N * B_TOTAL);      // 36*1024 ints

    dim3 grid1(NB_N, NB_B);
    hipLaunchKernelGGL(so3_partial_kernel, grid1, dim3(256), 0, stream, A, G, pval, pidx);
    hipLaunchKernelGGL(so3_final_kernel, dim3(B_TOTAL), dim3(64), 0, stream, G, pval, pidx, out);
}

// Round 3
// 128.435 us; speedup vs baseline: 1.0304x; 1.0304x over previous
//
#include <hip/hip_runtime.h>

#define B_TOTAL 1024
#define NGRID   294912
#define NBLK    1024                 // n-chunks / phase-1 blocks (4 per CU)
#define CHUNK   (NGRID / NBLK)       // 288 grid mats per block
#define BPT     4                    // b's owned per thread (256 thr * 4 = 1024 = all b)

// ws layout: B_TOTAL u64 keys. key = orderable(val)<<32 | ~idx
// atomicMax => max val, ties -> lowest idx (np.argmax semantics).

__global__ __launch_bounds__(256)
void so3_init_kernel(unsigned long long* __restrict__ ws) {
    int i = blockIdx.x * 256 + threadIdx.x;
    if (i < B_TOTAL) ws[i] = 0ull;   // below any valid key (val >= -3 maps well above 0)
}

__global__ __launch_bounds__(256, 4)
void so3_partial_kernel(const float* __restrict__ A,   // [1024][9]
                        const float* __restrict__ G,   // [NGRID][9]
                        unsigned long long* __restrict__ ws)
{
    __shared__ __align__(16) float sG[CHUNK * 9];      // 10368 B

    const int t  = threadIdx.x;
    const int n0 = blockIdx.x * CHUNK;

    // Stage this block's G chunk: 2592 floats = 648 float4, coalesced.
    {
        const float4* src = (const float4*)(G + (size_t)n0 * 9);
        float4*       dst = (float4*)sG;
        for (int i = t; i < (CHUNK * 9) / 4; i += 256)
            dst[i] = src[i];
    }

    // This thread's 4 A-matrices -> registers (once; 144 B contiguous, 16B-aligned).
    float a[BPT][9];
    {
        float4 r[9];
        const float4* av = (const float4*)(A + (size_t)t * BPT * 9);
        #pragma unroll
        for (int j = 0; j < 9; ++j) r[j] = av[j];
        const float* rf = (const float*)r;
        #pragma unroll
        for (int j = 0; j < BPT; ++j)
            #pragma unroll
            for (int k = 0; k < 9; ++k)
                a[j][k] = rf[j * 9 + k];
    }

    float best[BPT];
    int   bidx[BPT];
    #pragma unroll
    for (int j = 0; j < BPT; ++j) { best[j] = -1e30f; bidx[j] = 0; }

    __syncthreads();

    // Sweep the chunk. All lanes read the SAME sG address -> LDS broadcast,
    // conflict-free. n ascending + strict '>' keeps lowest index on ties.
    #pragma unroll 2
    for (int n = 0; n < CHUNK; ++n) {
        const float* g = &sG[n * 9];
        const float g0 = g[0], g1 = g[1], g2 = g[2],
                    g3 = g[3], g4 = g[4], g5 = g[5],
                    g6 = g[6], g7 = g[7], g8 = g[8];
        const int vn = n0 + n;
        #pragma unroll
        for (int j = 0; j < BPT; ++j) {
            // identical accumulation order to the round-2 kernel
            float d;
            d = a[j][0] * g0;
            d = fmaf(a[j][1], g1, d);
            d = fmaf(a[j][2], g2, d);
            d = fmaf(a[j][3], g3, d);
            d = fmaf(a[j][4], g4, d);
            d = fmaf(a[j][5], g5, d);
            d = fmaf(a[j][6], g6, d);
            d = fmaf(a[j][7], g7, d);
            d = fmaf(a[j][8], g8, d);
            if (d > best[j]) { best[j] = d; bidx[j] = vn; }
        }
    }

    // One packed atomicMax per owned b. Order-preserving float->uint:
    // nonneg: bits | 0x80000000 ; neg: ~bits. Lower word ~idx => ties pick min idx.
    #pragma unroll
    for (int j = 0; j < BPT; ++j) {
        unsigned u = __float_as_uint(best[j]);
        u = (u & 0x80000000u) ? ~u : (u | 0x80000000u);
        unsigned long long key =
            ((unsigned long long)u << 32) | (unsigned)(~bidx[j]);
        atomicMax(&ws[t * BPT + j], key);
    }
}

__global__ __launch_bounds__(256)
void so3_final_kernel(const float* __restrict__ G,
                      const unsigned long long* __restrict__ ws,
                      float* __restrict__ out)  // [1024] trace, then [1024*9] nearest
{
    int b = blockIdx.x * 256 + threadIdx.x;
    if (b >= B_TOTAL) return;
    unsigned long long key = ws[b];
    unsigned hi = (unsigned)(key >> 32);
    unsigned lo = (unsigned)key;
    unsigned bits = (hi & 0x80000000u) ? (hi ^ 0x80000000u) : ~hi;
    int idx = (int)(~lo);
    out[b] = __uint_as_float(bits);
    const float* g = G + (size_t)idx * 9;
    float* o = out + B_TOTAL + (size_t)b * 9;
    #pragma unroll
    for (int k = 0; k < 9; ++k) o[k] = g[k];
}

extern "C" void kernel_launch(void* const* d_in, const int* in_sizes, int n_in,
                              void* d_out, int out_size, void* d_ws, size_t ws_size,
                              hipStream_t stream) {
    const float* A = (const float*)d_in[0];   // rotMat [1024,3,3] fp32
    const float* G = (const float*)d_in[1];   // output_rotmats [294912,3,3] fp32
    float* out = (float*)d_out;
    unsigned long long* ws = (unsigned long long*)d_ws;  // 8 KB

    hipLaunchKernelGGL(so3_init_kernel,    dim3(4),    dim3(256), 0, stream, ws);
    hipLaunchKernelGGL(so3_partial_kernel, dim3(NBLK), dim3(256), 0, stream, A, G, ws);
    hipLaunchKernelGGL(so3_final_kernel,   dim3(4),    dim3(256), 0, stream, G, ws, out);
}

// Round 4
// 96.768 us; speedup vs baseline: 1.3676x; 1.3273x over previous
//
#include <hip/hip_runtime.h>

#define B_TOTAL 1024
#define NGRID   294912
#define NBLK    1024                 // phase-1 blocks (4 per CU)
#define CHUNK   (NGRID / NBLK)       // 288 grid mats per block
#define NTHR    128
#define BPT     8                    // b's per thread: thread t owns b = j*128 + t

// ws: B_TOTAL u64 keys. key = orderable(val)<<32 | ~idx.
// atomicMax => max val; ties -> lowest idx (np.argmax semantics).

__global__ __launch_bounds__(256)
void so3_init_kernel(unsigned long long* __restrict__ ws) {
    int i = blockIdx.x * 256 + threadIdx.x;
    if (i < B_TOTAL) ws[i] = 0ull;   // below any valid key (tr >= -3 => hi word >= 0x3FBF...)
}

__global__ __launch_bounds__(NTHR, 3)
void so3_partial_kernel(const float* __restrict__ A,   // [1024][9]
                        const float* __restrict__ G,   // [NGRID][9]
                        unsigned long long* __restrict__ ws)
{
    __shared__ __align__(16) float sG[CHUNK * 12];     // rows padded to 12 floats (48B)

    const int t  = threadIdx.x;
    const int n0 = blockIdx.x * CHUNK;

    // Stage G chunk (scalar, coalesced; padded dst). One-time per block.
    for (int i = t; i < CHUNK * 9; i += NTHR) {
        int row = i / 9, k = i - row * 9;
        sG[row * 12 + k] = G[(size_t)n0 * 9 + i];
    }

    // 8 A-matrices -> 72 registers. Fully static indexing, no casts
    // (round-3 bug: float4/reinterpret init demoted a[][] to scratch).
    float a[BPT][9];
    #pragma unroll
    for (int j = 0; j < BPT; ++j) {
        const float* ap = A + (size_t)(j * NTHR + t) * 9;
        #pragma unroll
        for (int k = 0; k < 9; ++k) a[j][k] = ap[k];
    }

    float best[BPT];
    int   bidx[BPT];
    #pragma unroll
    for (int j = 0; j < BPT; ++j) { best[j] = -1e30f; bidx[j] = 0; }

    __syncthreads();

    // Sweep chunk; all lanes read the SAME sG row -> LDS broadcast, conflict-free.
    // n ascending + strict '>' keeps lowest index on ties.
    #pragma unroll 2
    for (int n = 0; n < CHUNK; ++n) {
        const float4* gv = (const float4*)(sG + n * 12);   // 48B row, 16B aligned
        const float4 gA = gv[0], gB = gv[1];
        const float  g8 = sG[n * 12 + 8];
        const int vn = n0 + n;
        #pragma unroll
        for (int j = 0; j < BPT; ++j) {
            // identical accumulation order to round-2 kernel (bit-identical sims)
            float d;
            d = a[j][0] * gA.x;
            d = fmaf(a[j][1], gA.y, d);
            d = fmaf(a[j][2], gA.z, d);
            d = fmaf(a[j][3], gA.w, d);
            d = fmaf(a[j][4], gB.x, d);
            d = fmaf(a[j][5], gB.y, d);
            d = fmaf(a[j][6], gB.z, d);
            d = fmaf(a[j][7], gB.w, d);
            d = fmaf(a[j][8], g8, d);
            if (d > best[j]) { best[j] = d; bidx[j] = vn; }
        }
    }

    // Packed atomic per owned b; b = j*128 + t -> wave's atomics are contiguous.
    #pragma unroll
    for (int j = 0; j < BPT; ++j) {
        unsigned u = __float_as_uint(best[j]);
        u = (u & 0x80000000u) ? ~u : (u | 0x80000000u);
        unsigned long long key =
            ((unsigned long long)u << 32) | (unsigned)(~bidx[j]);
        atomicMax(&ws[j * NTHR + t], key);
    }
}

__global__ __launch_bounds__(256)
void so3_final_kernel(const float* __restrict__ G,
                      const unsigned long long* __restrict__ ws,
                      float* __restrict__ out)  // [1024] trace, then [1024*9] nearest
{
    int b = blockIdx.x * 256 + threadIdx.x;
    if (b >= B_TOTAL) return;
    unsigned long long key = ws[b];
    unsigned hi = (unsigned)(key >> 32);
    unsigned lo = (unsigned)key;
    unsigned bits = (hi & 0x80000000u) ? (hi ^ 0x80000000u) : ~hi;
    int idx = (int)(~lo);
    out[b] = __uint_as_float(bits);
    const float* g = G + (size_t)idx * 9;
    float* o = out + B_TOTAL + (size_t)b * 9;
    #pragma unroll
    for (int k = 0; k < 9; ++k) o[k] = g[k];
}

extern "C" void kernel_launch(void* const* d_in, const int* in_sizes, int n_in,
                              void* d_out, int out_size, void* d_ws, size_t ws_size,
                              hipStream_t stream) {
    const float* A = (const float*)d_in[0];   // rotMat [1024,3,3] fp32
    const float* G = (const float*)d_in[1];   // output_rotmats [294912,3,3] fp32
    float* out = (float*)d_out;
    unsigned long long* ws = (unsigned long long*)d_ws;  // 8 KB

    hipLaunchKernelGGL(so3_init_kernel,    dim3(4),    dim3(256), 0, stream, ws);
    hipLaunchKernelGGL(so3_partial_kernel, dim3(NBLK), dim3(NTHR), 0, stream, A, G, ws);
    hipLaunchKernelGGL(so3_final_kernel,   dim3(4),    dim3(256), 0, stream, G, ws, out);
}

// Round 5
// 85.941 us; speedup vs baseline: 1.5399x; 1.1260x over previous
//
#include <hip/hip_runtime.h>

#define B_TOTAL 1024
#define NGRID   294912
#define NBLK    2048                 // phase-1 blocks (8 per CU -> 16 waves/CU)
#define CHUNK   (NGRID / NBLK)       // 144 grid mats per block
#define NTHR    128
#define BPT     8                    // b's per thread: thread t owns b = j*128 + t

// ws: B_TOTAL u64 keys. key = orderable(val)<<32 | ~idx.
// atomicMax => max val; ties -> lowest idx (np.argmax semantics).

__global__ __launch_bounds__(256)
void so3_init_kernel(unsigned long long* __restrict__ ws) {
    int i = blockIdx.x * 256 + threadIdx.x;
    if (i < B_TOTAL) ws[i] = 0ull;   // below any valid key (tr >= -3 => hi word >= 0x3FBF...)
}

__global__ __launch_bounds__(NTHR, 4)
void so3_partial_kernel(const float* __restrict__ A,   // [1024][9]
                        const float* __restrict__ G,   // [NGRID][9]
                        unsigned long long* __restrict__ ws)
{
    __shared__ __align__(16) float sG[CHUNK * 12];     // rows padded to 12 floats (48B)

    const int t  = threadIdx.x;
    const int n0 = blockIdx.x * CHUNK;

    // Stage G chunk (scalar, coalesced src; padded dst).
    for (int i = t; i < CHUNK * 9; i += NTHR) {
        int row = i / 9, k = i - row * 9;
        sG[row * 12 + k] = G[(size_t)n0 * 9 + i];
    }

    // 8 A-matrices -> 72 registers. Fully static indexing, no pointer casts
    // (round-3 lesson: reinterpret-cast init demotes the array to scratch).
    float a[BPT][9];
    #pragma unroll
    for (int j = 0; j < BPT; ++j) {
        const float* ap = A + (size_t)(j * NTHR + t) * 9;
        #pragma unroll
        for (int k = 0; k < 9; ++k) a[j][k] = ap[k];
    }

    float best[BPT];
    int   bidx[BPT];
    #pragma unroll
    for (int j = 0; j < BPT; ++j) { best[j] = -1e30f; bidx[j] = 0; }

    __syncthreads();

    // Sweep chunk; all lanes read the SAME sG row -> LDS broadcast, conflict-free.
    // n ascending + strict '>' keeps lowest index on ties.
    #pragma unroll 2
    for (int n = 0; n < CHUNK; ++n) {
        const float4* gv = (const float4*)(sG + n * 12);   // 48B row, 16B aligned
        const float4 gA = gv[0], gB = gv[1];
        const float  g8 = sG[n * 12 + 8];
        const int vn = n0 + n;
        #pragma unroll
        for (int j = 0; j < BPT; ++j) {
            // identical accumulation order since round 2 (bit-identical sims)
            float d;
            d = a[j][0] * gA.x;
            d = fmaf(a[j][1], gA.y, d);
            d = fmaf(a[j][2], gA.z, d);
            d = fmaf(a[j][3], gA.w, d);
            d = fmaf(a[j][4], gB.x, d);
            d = fmaf(a[j][5], gB.y, d);
            d = fmaf(a[j][6], gB.z, d);
            d = fmaf(a[j][7], gB.w, d);
            d = fmaf(a[j][8], g8, d);
            if (d > best[j]) { best[j] = d; bidx[j] = vn; }
        }
    }

    // Packed max per owned b. Pre-check: ws is monotone (atomicMax from 0),
    // so a plain load only ever under-reads; "seen >= key" is a safe skip.
    #pragma unroll
    for (int j = 0; j < BPT; ++j) {
        unsigned u = __float_as_uint(best[j]);
        u = (u & 0x80000000u) ? ~u : (u | 0x80000000u);
        unsigned long long key =
            ((unsigned long long)u << 32) | (unsigned)(~bidx[j]);
        unsigned long long seen = ws[j * NTHR + t];
        if (key > seen) atomicMax(&ws[j * NTHR + t], key);
    }
}

__global__ __launch_bounds__(256)
void so3_final_kernel(const float* __restrict__ G,
                      const unsigned long long* __restrict__ ws,
                      float* __restrict__ out)  // [1024] trace, then [1024*9] nearest
{
    int b = blockIdx.x * 256 + threadIdx.x;
    if (b >= B_TOTAL) return;
    unsigned long long key = ws[b];
    unsigned hi = (unsigned)(key >> 32);
    unsigned lo = (unsigned)key;
    unsigned bits = (hi & 0x80000000u) ? (hi ^ 0x80000000u) : ~hi;
    int idx = (int)(~lo);
    out[b] = __uint_as_float(bits);
    const float* g = G + (size_t)idx * 9;
    float* o = out + B_TOTAL + (size_t)b * 9;
    #pragma unroll
    for (int k = 0; k < 9; ++k) o[k] = g[k];
}

extern "C" void kernel_launch(void* const* d_in, const int* in_sizes, int n_in,
                              void* d_out, int out_size, void* d_ws, size_t ws_size,
                              hipStream_t stream) {
    const float* A = (const float*)d_in[0];   // rotMat [1024,3,3] fp32
    const float* G = (const float*)d_in[1];   // output_rotmats [294912,3,3] fp32
    float* out = (float*)d_out;
    unsigned long long* ws = (unsigned long long*)d_ws;  // 8 KB

    hipLaunchKernelGGL(so3_init_kernel,    dim3(4),    dim3(256), 0, stream, ws);
    hipLaunchKernelGGL(so3_partial_kernel, dim3(NBLK), dim3(NTHR), 0, stream, A, G, ws);
    hipLaunchKernelGGL(so3_final_kernel,   dim3(4),    dim3(256), 0, stream, G, ws, out);
}